// Round 1
// baseline (408.783 us; speedup 1.0000x reference)
//
#include <hip/hip_runtime.h>

#define LR    1e-3f
#define BETA1 0.9f
#define BETA2 0.999f
#define EPS   1e-8f

__global__ void __launch_bounds__(256)
adam_kernel(const float4* __restrict__ p,
            const float4* __restrict__ g,
            const float4* __restrict__ m,
            const float4* __restrict__ v,
            const int* __restrict__ step_ptr,
            float4* __restrict__ p_out,
            float4* __restrict__ m_out,
            float4* __restrict__ v_out,
            long long n4) {
    // Bias corrections: step is small (post-increment counter), compute
    // 1 - beta^step once per thread in double for exactness.
    const int step = *step_ptr;
    double b1p = 1.0, b2p = 1.0;
    for (int i = 0; i < step; ++i) { b1p *= (double)BETA1; b2p *= (double)BETA2; }
    const float inv_bc1 = (float)(1.0 / (1.0 - b1p));
    const float inv_bc2 = (float)(1.0 / (1.0 - b2p));

    const long long tid    = (long long)blockIdx.x * blockDim.x + threadIdx.x;
    const long long stride = (long long)gridDim.x * blockDim.x;

    for (long long i = tid; i < n4; i += stride) {
        const float4 pv = p[i];
        const float4 gv = g[i];
        const float4 mv = m[i];
        const float4 vv = v[i];

        float4 mn, vn, pn;
        #pragma unroll
        for (int j = 0; j < 4; ++j) {
            const float gj = (&gv.x)[j];
            const float mj = (&mv.x)[j];
            const float vj = (&vv.x)[j];
            const float pj = (&pv.x)[j];

            const float m_new = (1.0f - BETA1) * gj + BETA1 * mj;
            const float v_new = (1.0f - BETA2) * gj * gj + BETA2 * vj;
            const float m_hat = m_new * inv_bc1;
            const float v_hat = v_new * inv_bc2;
            const float p_new = pj - (LR / (sqrtf(v_hat) + EPS)) * m_hat;

            (&mn.x)[j] = m_new;
            (&vn.x)[j] = v_new;
            (&pn.x)[j] = p_new;
        }

        p_out[i] = pn;
        m_out[i] = mn;
        v_out[i] = vn;
    }
}

// Scalar tail kernel (n not divisible by 4 — defensive; current shape is divisible).
__global__ void adam_tail_kernel(const float* __restrict__ p,
                                 const float* __restrict__ g,
                                 const float* __restrict__ m,
                                 const float* __restrict__ v,
                                 const int* __restrict__ step_ptr,
                                 float* __restrict__ p_out,
                                 float* __restrict__ m_out,
                                 float* __restrict__ v_out,
                                 long long start, long long n) {
    const int step = *step_ptr;
    double b1p = 1.0, b2p = 1.0;
    for (int i = 0; i < step; ++i) { b1p *= (double)BETA1; b2p *= (double)BETA2; }
    const float inv_bc1 = (float)(1.0 / (1.0 - b1p));
    const float inv_bc2 = (float)(1.0 / (1.0 - b2p));

    long long i = start + blockIdx.x * blockDim.x + threadIdx.x;
    if (i < n) {
        const float gj = g[i], mj = m[i], vj = v[i], pj = p[i];
        const float m_new = (1.0f - BETA1) * gj + BETA1 * mj;
        const float v_new = (1.0f - BETA2) * gj * gj + BETA2 * vj;
        const float m_hat = m_new * inv_bc1;
        const float v_hat = v_new * inv_bc2;
        p_out[i] = pj - (LR / (sqrtf(v_hat) + EPS)) * m_hat;
        m_out[i] = m_new;
        v_out[i] = v_new;
    }
}

extern "C" void kernel_launch(void* const* d_in, const int* in_sizes, int n_in,
                              void* d_out, int out_size, void* d_ws, size_t ws_size,
                              hipStream_t stream) {
    const float* p    = (const float*)d_in[0];
    const float* g    = (const float*)d_in[1];
    const float* m    = (const float*)d_in[2];
    const float* v    = (const float*)d_in[3];
    const int*   step = (const int*)d_in[4];

    const long long n = (long long)in_sizes[0];

    // d_out = [p_new | m_new | v_new], each n floats.
    float* p_out = (float*)d_out;
    float* m_out = p_out + n;
    float* v_out = m_out + n;

    const long long n4 = n / 4;
    const int block = 256;
    // Memory-bound: cap grid ~2048 blocks, grid-stride the rest (G11).
    long long want = (n4 + block - 1) / block;
    int grid = (int)(want < 2048 ? (want > 0 ? want : 1) : 2048);

    if (n4 > 0) {
        adam_kernel<<<grid, block, 0, stream>>>(
            (const float4*)p, (const float4*)g, (const float4*)m, (const float4*)v,
            step, (float4*)p_out, (float4*)m_out, (float4*)v_out, n4);
    }

    const long long tail_start = n4 * 4;
    if (tail_start < n) {
        const long long tail = n - tail_start;
        adam_tail_kernel<<<(int)((tail + block - 1) / block), block, 0, stream>>>(
            p, g, m, v, step, p_out, m_out, v_out, tail_start, n);
    }
}

// Round 3
// 358.225 us; speedup vs baseline: 1.1411x; 1.1411x over previous
//
#include <hip/hip_runtime.h>

#define LR    1e-3f
#define BETA1 0.9f
#define BETA2 0.999f
#define EPS   1e-8f

// Native vector type — __builtin_nontemporal_* requires a scalar/vector type,
// not HIP's struct-based float4.
typedef float fvec4 __attribute__((ext_vector_type(4)));

__device__ __forceinline__ fvec4 nt_load4(const fvec4* p) {
    return __builtin_nontemporal_load(p);
}
__device__ __forceinline__ void nt_store4(fvec4* p, fvec4 v) {
    __builtin_nontemporal_store(v, p);
}

__device__ __forceinline__ void adam_elem4(const fvec4& pv, const fvec4& gv,
                                           const fvec4& mv, const fvec4& vv,
                                           float inv_bc1, float inv_bc2,
                                           fvec4& pn, fvec4& mn, fvec4& vn) {
    #pragma unroll
    for (int j = 0; j < 4; ++j) {
        const float gj = gv[j];
        const float mj = mv[j];
        const float vj = vv[j];
        const float pj = pv[j];

        const float m_new = (1.0f - BETA1) * gj + BETA1 * mj;
        const float v_new = (1.0f - BETA2) * gj * gj + BETA2 * vj;
        const float m_hat = m_new * inv_bc1;
        const float v_hat = v_new * inv_bc2;
        const float p_new = pj - (LR / (sqrtf(v_hat) + EPS)) * m_hat;

        mn[j] = m_new;
        vn[j] = v_new;
        pn[j] = p_new;
    }
}

__global__ void __launch_bounds__(256)
adam_kernel(const fvec4* __restrict__ p,
            const fvec4* __restrict__ g,
            const fvec4* __restrict__ m,
            const fvec4* __restrict__ v,
            const int* __restrict__ step_ptr,
            fvec4* __restrict__ p_out,
            fvec4* __restrict__ m_out,
            fvec4* __restrict__ v_out,
            long long n4) {
    const int step = *step_ptr;
    double b1p = 1.0, b2p = 1.0;
    for (int i = 0; i < step; ++i) { b1p *= (double)BETA1; b2p *= (double)BETA2; }
    const float inv_bc1 = (float)(1.0 / (1.0 - b1p));
    const float inv_bc2 = (float)(1.0 / (1.0 - b2p));

    const long long tid    = (long long)blockIdx.x * blockDim.x + threadIdx.x;
    const long long stride = (long long)gridDim.x * blockDim.x;

    long long i = tid;

    // Unrolled-by-2 main loop: 8 nontemporal loads in flight before compute.
    for (; i + stride < n4; i += 2 * stride) {
        const long long i1 = i + stride;
        const fvec4 pv0 = nt_load4(&p[i]);
        const fvec4 gv0 = nt_load4(&g[i]);
        const fvec4 mv0 = nt_load4(&m[i]);
        const fvec4 vv0 = nt_load4(&v[i]);
        const fvec4 pv1 = nt_load4(&p[i1]);
        const fvec4 gv1 = nt_load4(&g[i1]);
        const fvec4 mv1 = nt_load4(&m[i1]);
        const fvec4 vv1 = nt_load4(&v[i1]);

        fvec4 pn0, mn0, vn0, pn1, mn1, vn1;
        adam_elem4(pv0, gv0, mv0, vv0, inv_bc1, inv_bc2, pn0, mn0, vn0);
        adam_elem4(pv1, gv1, mv1, vv1, inv_bc1, inv_bc2, pn1, mn1, vn1);

        nt_store4(&p_out[i],  pn0);
        nt_store4(&m_out[i],  mn0);
        nt_store4(&v_out[i],  vn0);
        nt_store4(&p_out[i1], pn1);
        nt_store4(&m_out[i1], mn1);
        nt_store4(&v_out[i1], vn1);
    }
    // Remainder (at most one stride-step).
    for (; i < n4; i += stride) {
        const fvec4 pv = nt_load4(&p[i]);
        const fvec4 gv = nt_load4(&g[i]);
        const fvec4 mv = nt_load4(&m[i]);
        const fvec4 vv = nt_load4(&v[i]);
        fvec4 pn, mn, vn;
        adam_elem4(pv, gv, mv, vv, inv_bc1, inv_bc2, pn, mn, vn);
        nt_store4(&p_out[i], pn);
        nt_store4(&m_out[i], mn);
        nt_store4(&v_out[i], vn);
    }
}

// Scalar tail kernel (n not divisible by 4 — defensive; current shape is divisible).
__global__ void adam_tail_kernel(const float* __restrict__ p,
                                 const float* __restrict__ g,
                                 const float* __restrict__ m,
                                 const float* __restrict__ v,
                                 const int* __restrict__ step_ptr,
                                 float* __restrict__ p_out,
                                 float* __restrict__ m_out,
                                 float* __restrict__ v_out,
                                 long long start, long long n) {
    const int step = *step_ptr;
    double b1p = 1.0, b2p = 1.0;
    for (int i = 0; i < step; ++i) { b1p *= (double)BETA1; b2p *= (double)BETA2; }
    const float inv_bc1 = (float)(1.0 / (1.0 - b1p));
    const float inv_bc2 = (float)(1.0 / (1.0 - b2p));

    long long i = start + blockIdx.x * blockDim.x + threadIdx.x;
    if (i < n) {
        const float gj = g[i], mj = m[i], vj = v[i], pj = p[i];
        const float m_new = (1.0f - BETA1) * gj + BETA1 * mj;
        const float v_new = (1.0f - BETA2) * gj * gj + BETA2 * vj;
        const float m_hat = m_new * inv_bc1;
        const float v_hat = v_new * inv_bc2;
        p_out[i] = pj - (LR / (sqrtf(v_hat) + EPS)) * m_hat;
        m_out[i] = m_new;
        v_out[i] = v_new;
    }
}

extern "C" void kernel_launch(void* const* d_in, const int* in_sizes, int n_in,
                              void* d_out, int out_size, void* d_ws, size_t ws_size,
                              hipStream_t stream) {
    const float* p    = (const float*)d_in[0];
    const float* g    = (const float*)d_in[1];
    const float* m    = (const float*)d_in[2];
    const float* v    = (const float*)d_in[3];
    const int*   step = (const int*)d_in[4];

    const long long n = (long long)in_sizes[0];

    // d_out = [p_new | m_new | v_new], each n floats.
    float* p_out = (float*)d_out;
    float* m_out = p_out + n;
    float* v_out = m_out + n;

    const long long n4 = n / 4;
    const int block = 256;
    long long want = (n4 + block - 1) / block;
    int grid = (int)(want < 2048 ? (want > 0 ? want : 1) : 2048);

    if (n4 > 0) {
        adam_kernel<<<grid, block, 0, stream>>>(
            (const fvec4*)p, (const fvec4*)g, (const fvec4*)m, (const fvec4*)v,
            step, (fvec4*)p_out, (fvec4*)m_out, (fvec4*)v_out, n4);
    }

    const long long tail_start = n4 * 4;
    if (tail_start < n) {
        const long long tail = n - tail_start;
        adam_tail_kernel<<<(int)((tail + block - 1) / block), block, 0, stream>>>(
            p, g, m, v, step, p_out, m_out, v_out, tail_start, n);
    }
}

// Round 4
// 342.384 us; speedup vs baseline: 1.1939x; 1.0463x over previous
//
#include <hip/hip_runtime.h>

#define LR    1e-3f
#define BETA1 0.9f
#define BETA2 0.999f
#define EPS   1e-8f

// Native vector type — __builtin_nontemporal_* requires a scalar/vector type,
// not HIP's struct-based float4.
typedef float fvec4 __attribute__((ext_vector_type(4)));

__device__ __forceinline__ fvec4 nt_load4(const fvec4* p) {
    return __builtin_nontemporal_load(p);
}
__device__ __forceinline__ void nt_store4(fvec4* p, fvec4 v) {
    __builtin_nontemporal_store(v, p);
}

__device__ __forceinline__ void adam_elem4(const fvec4& pv, const fvec4& gv,
                                           const fvec4& mv, const fvec4& vv,
                                           float inv_bc1, float inv_bc2,
                                           fvec4& pn, fvec4& mn, fvec4& vn) {
    #pragma unroll
    for (int j = 0; j < 4; ++j) {
        const float gj = gv[j];
        const float mj = mv[j];
        const float vj = vv[j];
        const float pj = pv[j];

        const float m_new = (1.0f - BETA1) * gj + BETA1 * mj;
        const float v_new = (1.0f - BETA2) * gj * gj + BETA2 * vj;
        const float m_hat = m_new * inv_bc1;
        const float v_hat = v_new * inv_bc2;
        const float p_new = pj - (LR / (sqrtf(v_hat) + EPS)) * m_hat;

        mn[j] = m_new;
        vn[j] = v_new;
        pn[j] = p_new;
    }
}

__global__ void __launch_bounds__(256)
adam_kernel(const fvec4* __restrict__ p,
            const fvec4* __restrict__ g,
            const fvec4* __restrict__ m,
            const fvec4* __restrict__ v,
            const int* __restrict__ step_ptr,
            fvec4* __restrict__ p_out,
            fvec4* __restrict__ m_out,
            fvec4* __restrict__ v_out,
            long long n4) {
    const int step = *step_ptr;
    double b1p = 1.0, b2p = 1.0;
    for (int i = 0; i < step; ++i) { b1p *= (double)BETA1; b2p *= (double)BETA2; }
    const float inv_bc1 = (float)(1.0 / (1.0 - b1p));
    const float inv_bc2 = (float)(1.0 / (1.0 - b2p));

    const long long tid    = (long long)blockIdx.x * blockDim.x + threadIdx.x;
    const long long stride = (long long)gridDim.x * blockDim.x;

    long long i = tid;

    // Unrolled-by-4 main loop: 16 nontemporal loads in flight before compute.
    for (; i + 3 * stride < n4; i += 4 * stride) {
        const long long i0 = i;
        const long long i1 = i + stride;
        const long long i2 = i + 2 * stride;
        const long long i3 = i + 3 * stride;

        const fvec4 pv0 = nt_load4(&p[i0]);
        const fvec4 gv0 = nt_load4(&g[i0]);
        const fvec4 mv0 = nt_load4(&m[i0]);
        const fvec4 vv0 = nt_load4(&v[i0]);
        const fvec4 pv1 = nt_load4(&p[i1]);
        const fvec4 gv1 = nt_load4(&g[i1]);
        const fvec4 mv1 = nt_load4(&m[i1]);
        const fvec4 vv1 = nt_load4(&v[i1]);
        const fvec4 pv2 = nt_load4(&p[i2]);
        const fvec4 gv2 = nt_load4(&g[i2]);
        const fvec4 mv2 = nt_load4(&m[i2]);
        const fvec4 vv2 = nt_load4(&v[i2]);
        const fvec4 pv3 = nt_load4(&p[i3]);
        const fvec4 gv3 = nt_load4(&g[i3]);
        const fvec4 mv3 = nt_load4(&m[i3]);
        const fvec4 vv3 = nt_load4(&v[i3]);

        fvec4 pn0, mn0, vn0, pn1, mn1, vn1, pn2, mn2, vn2, pn3, mn3, vn3;
        adam_elem4(pv0, gv0, mv0, vv0, inv_bc1, inv_bc2, pn0, mn0, vn0);
        adam_elem4(pv1, gv1, mv1, vv1, inv_bc1, inv_bc2, pn1, mn1, vn1);
        adam_elem4(pv2, gv2, mv2, vv2, inv_bc1, inv_bc2, pn2, mn2, vn2);
        adam_elem4(pv3, gv3, mv3, vv3, inv_bc1, inv_bc2, pn3, mn3, vn3);

        nt_store4(&p_out[i0], pn0);
        nt_store4(&m_out[i0], mn0);
        nt_store4(&v_out[i0], vn0);
        nt_store4(&p_out[i1], pn1);
        nt_store4(&m_out[i1], mn1);
        nt_store4(&v_out[i1], vn1);
        nt_store4(&p_out[i2], pn2);
        nt_store4(&m_out[i2], mn2);
        nt_store4(&v_out[i2], vn2);
        nt_store4(&p_out[i3], pn3);
        nt_store4(&m_out[i3], mn3);
        nt_store4(&v_out[i3], vn3);
    }
    // Remainder.
    for (; i < n4; i += stride) {
        const fvec4 pv = nt_load4(&p[i]);
        const fvec4 gv = nt_load4(&g[i]);
        const fvec4 mv = nt_load4(&m[i]);
        const fvec4 vv = nt_load4(&v[i]);
        fvec4 pn, mn, vn;
        adam_elem4(pv, gv, mv, vv, inv_bc1, inv_bc2, pn, mn, vn);
        nt_store4(&p_out[i], pn);
        nt_store4(&m_out[i], mn);
        nt_store4(&v_out[i], vn);
    }
}

// Scalar tail kernel (n not divisible by 4 — defensive; current shape is divisible).
__global__ void adam_tail_kernel(const float* __restrict__ p,
                                 const float* __restrict__ g,
                                 const float* __restrict__ m,
                                 const float* __restrict__ v,
                                 const int* __restrict__ step_ptr,
                                 float* __restrict__ p_out,
                                 float* __restrict__ m_out,
                                 float* __restrict__ v_out,
                                 long long start, long long n) {
    const int step = *step_ptr;
    double b1p = 1.0, b2p = 1.0;
    for (int i = 0; i < step; ++i) { b1p *= (double)BETA1; b2p *= (double)BETA2; }
    const float inv_bc1 = (float)(1.0 / (1.0 - b1p));
    const float inv_bc2 = (float)(1.0 / (1.0 - b2p));

    long long i = start + blockIdx.x * blockDim.x + threadIdx.x;
    if (i < n) {
        const float gj = g[i], mj = m[i], vj = v[i], pj = p[i];
        const float m_new = (1.0f - BETA1) * gj + BETA1 * mj;
        const float v_new = (1.0f - BETA2) * gj * gj + BETA2 * vj;
        const float m_hat = m_new * inv_bc1;
        const float v_hat = v_new * inv_bc2;
        p_out[i] = pj - (LR / (sqrtf(v_hat) + EPS)) * m_hat;
        m_out[i] = m_new;
        v_out[i] = v_new;
    }
}

extern "C" void kernel_launch(void* const* d_in, const int* in_sizes, int n_in,
                              void* d_out, int out_size, void* d_ws, size_t ws_size,
                              hipStream_t stream) {
    const float* p    = (const float*)d_in[0];
    const float* g    = (const float*)d_in[1];
    const float* m    = (const float*)d_in[2];
    const float* v    = (const float*)d_in[3];
    const int*   step = (const int*)d_in[4];

    const long long n = (long long)in_sizes[0];

    // d_out = [p_new | m_new | v_new], each n floats.
    float* p_out = (float*)d_out;
    float* m_out = p_out + n;
    float* v_out = m_out + n;

    const long long n4 = n / 4;
    const int block = 256;
    long long want = (n4 + block - 1) / block;
    int grid = (int)(want < 2048 ? (want > 0 ? want : 1) : 2048);

    if (n4 > 0) {
        adam_kernel<<<grid, block, 0, stream>>>(
            (const fvec4*)p, (const fvec4*)g, (const fvec4*)m, (const fvec4*)v,
            step, (fvec4*)p_out, (fvec4*)m_out, (fvec4*)v_out, n4);
    }

    const long long tail_start = n4 * 4;
    if (tail_start < n) {
        const long long tail = n - tail_start;
        adam_tail_kernel<<<(int)((tail + block - 1) / block), block, 0, stream>>>(
            p, g, m, v, step, p_out, m_out, v_out, tail_start, n);
    }
}